// Round 2
// baseline (40970.892 us; speedup 1.0000x reference)
//
#include <hip/hip_runtime.h>

#define H      51
#define T_IN   512
#define T_TOT  576          // 512 + 64 future
#define PITCH  52           // fp32 LDS row pitch: 13 float4; stride 20 mod 32 banks -> even spread
#define NROWS  765          // LDS rows: Whh1(204) Wih2(204) Wih3(204) Whh3 f,g,o(153)
#define LDSFL  (NROWS * PITCH)   // 39,780 floats = 159,120 B

// W_hh2 gates g,o staged transposed+padded: [k][lane], coalesced per-k loads.
__device__ float g_w2gT[52 * 64];
__device__ float g_w2oT[52 * 64];

__device__ __forceinline__ float bf2f(unsigned short u) {
    return __uint_as_float(((unsigned int)u) << 16);
}
__device__ __forceinline__ unsigned short f2bf(float f) {
    unsigned int u = __float_as_uint(f);
    u += 0x7fffu + ((u >> 16) & 1u);
    return (unsigned short)(u >> 16);
}
__device__ __forceinline__ float wget(const void* p, int i, bool is16) {
    return is16 ? bf2f(((const unsigned short*)p)[i]) : ((const float*)p)[i];
}
__device__ __forceinline__ float rl(float v, int k) {
    return __uint_as_float((unsigned int)__builtin_amdgcn_readlane((int)__float_as_uint(v), k));
}
__device__ __forceinline__ float sigm(float x) {
    x = fminf(fmaxf(x, -30.f), 30.f);
    return 1.f / (1.f + __expf(-x));
}
__device__ __forceinline__ float tanh_f(float x) {
    x = fminf(fmaxf(x, -15.f), 15.f);
    float e = __expf(2.f * x);
    return (e - 1.f) / (e + 1.f);
}
__device__ __forceinline__ float f4e(float4 v, int i) {
    return i == 0 ? v.x : i == 1 ? v.y : i == 2 ? v.z : v.w;
}
__device__ __forceinline__ float4 wld4(const void* p, int row, int kb, bool is16) {
    float4 r;
    int c0 = 4 * kb;
    r.x = (c0 + 0 < H) ? wget(p, row * H + c0 + 0, is16) : 0.f;
    r.y = (c0 + 1 < H) ? wget(p, row * H + c0 + 1, is16) : 0.f;
    r.z = (c0 + 2 < H) ? wget(p, row * H + c0 + 2, is16) : 0.f;
    r.w = (c0 + 3 < H) ? wget(p, row * H + c0 + 3, is16) : 0.f;
    return r;
}

#define L13(M) M(0) M(1) M(2) M(3) M(4) M(5) M(6) M(7) M(8) M(9) M(10) M(11) M(12)

extern "C" __global__ void __launch_bounds__(256, 1)
lstm3_kernel(const void* g_in,  const void* g_Wih1, const void* g_Whh1,
             const void* g_bih1, const void* g_bhh1,
             const void* g_Wih2, const void* g_Whh2, const void* g_bih2, const void* g_bhh2,
             const void* g_Wih3, const void* g_Whh3, const void* g_bih3, const void* g_bhh3,
             const void* g_Wlin, const void* g_blin, void* g_out)
{
    extern __shared__ float smem[];

    const int tid  = threadIdx.x;
    const int lane = tid & 63;
    const int wid  = tid >> 6;
    const int e    = blockIdx.x * 4 + wid;
    const int jeff = (lane < H) ? lane : (H - 1);

    // ---- dtype sniff (proven round 1: resolves fp32 on this harness)
    bool is16 = true;
    {
        const unsigned short* p = (const unsigned short*)g_Wih1;
        for (int i = 0; i < 204; ++i) {
            float v = fabsf(bf2f(p[i]));
            if (!(v < 0.2f)) is16 = false;
        }
    }

    // ---- LDS staging: rows [Whh1 0..203 | Wih2 0..203 | Wih3 0..203 | Whh3 51..203]
    for (int i = tid; i < LDSFL; i += 256) {
        int r = i / PITCH, k = i - r * PITCH;
        const void* src; int srow;
        if (r < 204)      { src = g_Whh1; srow = r; }
        else if (r < 408) { src = g_Wih2; srow = r - 204; }
        else if (r < 612) { src = g_Wih3; srow = r - 408; }
        else              { src = g_Whh3; srow = 51 + (r - 612); }
        smem[i] = (k < H) ? wget(src, srow * H + k, is16) : 0.f;
    }
    // ---- W_hh2 g,o transposed into device-global (identical data from every block)
    for (int i = tid; i < 52 * 64; i += 256) {
        int k = i >> 6, j = i & 63;
        bool ok = (k < H) && (j < H);
        g_w2gT[i] = ok ? wget(g_Whh2, (2 * H + j) * H + k, is16) : 0.f;
        g_w2oT[i] = ok ? wget(g_Whh2, (3 * H + j) * H + k, is16) : 0.f;
    }
    __syncthreads();

    // ---- register weights (macro-literal indexing only -> guaranteed SSA/regs)
    float4 w2i[13], w2f[13], w3i[13];
#define WINIT(kb) \
    w2i[kb] = wld4(g_Whh2, 0 * H + jeff, kb, is16); \
    w2f[kb] = wld4(g_Whh2, 1 * H + jeff, kb, is16); \
    w3i[kb] = wld4(g_Whh3, 0 * H + jeff, kb, is16);
    L13(WINIT)

    float b1r[4], b2r[4], b3r[4], wi1r[4];
#pragma unroll
    for (int g = 0; g < 4; ++g) {
        int r = g * H + jeff;
        b1r[g]  = wget(g_bih1, r, is16) + wget(g_bhh1, r, is16);
        b2r[g]  = wget(g_bih2, r, is16) + wget(g_bhh2, r, is16);
        b3r[g]  = wget(g_bih3, r, is16) + wget(g_bhh3, r, is16);
        wi1r[g] = wget(g_Wih1, r, is16);
    }
    float wlinr = (lane < H) ? wget(g_Wlin, lane, is16) : 0.f;
    float blinr = wget(g_blin, 0, is16);

    const float4* A1_0 = (const float4*)(smem + (0 * H + jeff) * PITCH);
    const float4* A1_1 = (const float4*)(smem + (1 * H + jeff) * PITCH);
    const float4* A1_2 = (const float4*)(smem + (2 * H + jeff) * PITCH);
    const float4* A1_3 = (const float4*)(smem + (3 * H + jeff) * PITCH);
    const float4* A2_0 = (const float4*)(smem + (204 + 0 * H + jeff) * PITCH);
    const float4* A2_1 = (const float4*)(smem + (204 + 1 * H + jeff) * PITCH);
    const float4* A2_2 = (const float4*)(smem + (204 + 2 * H + jeff) * PITCH);
    const float4* A2_3 = (const float4*)(smem + (204 + 3 * H + jeff) * PITCH);
    const float4* A3_0 = (const float4*)(smem + (408 + 0 * H + jeff) * PITCH);
    const float4* A3_1 = (const float4*)(smem + (408 + 1 * H + jeff) * PITCH);
    const float4* A3_2 = (const float4*)(smem + (408 + 2 * H + jeff) * PITCH);
    const float4* A3_3 = (const float4*)(smem + (408 + 3 * H + jeff) * PITCH);
    const float4* A3f  = (const float4*)(smem + (612 +       jeff) * PITCH);
    const float4* A3g  = (const float4*)(smem + (612 + 51  + jeff) * PITCH);
    const float4* A3o  = (const float4*)(smem + (612 + 102 + jeff) * PITCH);

    float h1 = 0.f, c1 = 0.f, h2 = 0.f, c2 = 0.f, h3 = 0.f, c3 = 0.f;
    float xfb = 0.f;
    const unsigned short* in16 = (const unsigned short*)g_in + (size_t)e * T_IN;
    const float*          in32 = (const float*)g_in          + (size_t)e * T_IN;
    unsigned short*       o16  = (unsigned short*)g_out      + (size_t)e * T_TOT;
    float*                o32  = (float*)g_out               + (size_t)e * T_TOT;

#define ST1(kb, i) { float hs = rl(h1, 4 * kb + i); \
    a0 = fmaf(f4e(u0, i), hs, a0); a1 = fmaf(f4e(u1, i), hs, a1); \
    a2 = fmaf(f4e(u2, i), hs, a2); a3 = fmaf(f4e(u3, i), hs, a3); }
#define L1KB(kb) { float4 u0 = A1_0[kb], u1 = A1_1[kb], u2 = A1_2[kb], u3 = A1_3[kb]; \
    ST1(kb, 0) ST1(kb, 1) ST1(kb, 2) ST1(kb, 3) }

#define ST2(kb, i) { float hs1 = rl(h1, 4 * kb + i); \
    a0 = fmaf(f4e(u0, i), hs1, a0); a1 = fmaf(f4e(u1, i), hs1, a1); \
    a2 = fmaf(f4e(u2, i), hs1, a2); a3 = fmaf(f4e(u3, i), hs1, a3); \
    float hs2 = rl(h2, 4 * kb + i); \
    a0 = fmaf(f4e(w2i[kb], i), hs2, a0); a1 = fmaf(f4e(w2f[kb], i), hs2, a1); \
    a2 = fmaf(g_w2gT[(4 * kb + i) * 64 + lane], hs2, a2); \
    a3 = fmaf(g_w2oT[(4 * kb + i) * 64 + lane], hs2, a3); }
#define L2KB(kb) { float4 u0 = A2_0[kb], u1 = A2_1[kb], u2 = A2_2[kb], u3 = A2_3[kb]; \
    ST2(kb, 0) ST2(kb, 1) ST2(kb, 2) ST2(kb, 3) }

#define ST3(kb, i) { float hs2 = rl(h2, 4 * kb + i); \
    a0 = fmaf(f4e(u0, i), hs2, a0); a1 = fmaf(f4e(u1, i), hs2, a1); \
    a2 = fmaf(f4e(u2, i), hs2, a2); a3 = fmaf(f4e(u3, i), hs2, a3); \
    float hs3 = rl(h3, 4 * kb + i); \
    a0 = fmaf(f4e(w3i[kb], i), hs3, a0); a1 = fmaf(f4e(v1, i), hs3, a1); \
    a2 = fmaf(f4e(v2, i), hs3, a2); a3 = fmaf(f4e(v3, i), hs3, a3); }
#define L3KB(kb) { float4 u0 = A3_0[kb], u1 = A3_1[kb], u2 = A3_2[kb], u3 = A3_3[kb]; \
    float4 v1 = A3f[kb], v2 = A3g[kb], v3 = A3o[kb]; \
    ST3(kb, 0) ST3(kb, 1) ST3(kb, 2) ST3(kb, 3) }

    for (int t = 0; t < T_TOT; ++t) {
        float x = (t < T_IN) ? (is16 ? bf2f(in16[t]) : in32[t]) : xfb;

        float a0, a1, a2, a3;
        // ---------- layer 1 ----------
        a0 = fmaf(wi1r[0], x, b1r[0]);
        a1 = fmaf(wi1r[1], x, b1r[1]);
        a2 = fmaf(wi1r[2], x, b1r[2]);
        a3 = fmaf(wi1r[3], x, b1r[3]);
        L13(L1KB)
        {
            float ig = sigm(a0), fg = sigm(a1), gg = tanh_f(a2), og = sigm(a3);
            c1 = fg * c1 + ig * gg;
            h1 = og * tanh_f(c1);
        }
        // ---------- layer 2 ----------
        a0 = b2r[0]; a1 = b2r[1]; a2 = b2r[2]; a3 = b2r[3];
        L13(L2KB)
        {
            float ig = sigm(a0), fg = sigm(a1), gg = tanh_f(a2), og = sigm(a3);
            c2 = fg * c2 + ig * gg;
            h2 = og * tanh_f(c2);
        }
        // ---------- layer 3 ----------
        a0 = b3r[0]; a1 = b3r[1]; a2 = b3r[2]; a3 = b3r[3];
        L13(L3KB)
        {
            float ig = sigm(a0), fg = sigm(a1), gg = tanh_f(a2), og = sigm(a3);
            c3 = fg * c3 + ig * gg;
            h3 = og * tanh_f(c3);
        }
        // ---------- linear head + feedback ----------
        float s = wlinr * h3;
        s += __shfl_xor(s, 32, 64);
        s += __shfl_xor(s, 16, 64);
        s += __shfl_xor(s, 8, 64);
        s += __shfl_xor(s, 4, 64);
        s += __shfl_xor(s, 2, 64);
        s += __shfl_xor(s, 1, 64);
        float ov = s + blinr;
        xfb = ov;
        if (lane == 0) {
            if (is16) o16[t] = f2bf(ov);
            else      o32[t] = ov;
        }
    }
}

extern "C" void kernel_launch(void* const* d_in, const int* in_sizes, int n_in,
                              void* d_out, int out_size, void* d_ws, size_t ws_size,
                              hipStream_t stream) {
    (void)in_sizes; (void)n_in; (void)d_ws; (void)ws_size; (void)out_size;
    size_t shmem = LDSFL * sizeof(float);   // 159,120 B
    hipFuncSetAttribute((const void*)lstm3_kernel,
                        hipFuncAttributeMaxDynamicSharedMemorySize, (int)shmem);
    lstm3_kernel<<<dim3(256), dim3(256), shmem, stream>>>(
        d_in[0],  d_in[1],  d_in[2],  d_in[3],  d_in[4],
        d_in[5],  d_in[6],  d_in[7],  d_in[8],
        d_in[9],  d_in[10], d_in[11], d_in[12],
        d_in[13], d_in[14], d_out);
}

// Round 3
// 3107.743 us; speedup vs baseline: 13.1835x; 13.1835x over previous
//
#include <hip/hip_runtime.h>

#define H      51
#define T_IN   512
#define T_TOT  576          // 512 + 64 future
#define PITCH  52           // fp32 LDS row pitch: 13 float4 blocks
#define NROWS  765          // Whh1(204) Wih2(204) Wih3(204) Whh3 f,g,o(153)
#define LDSFL  (NROWS * PITCH)   // 39,780 floats = 159,120 B  (cap 163,840)

__device__ __forceinline__ float bf2f(unsigned short u) {
    return __uint_as_float(((unsigned int)u) << 16);
}
__device__ __forceinline__ unsigned short f2bf(float f) {
    unsigned int u = __float_as_uint(f);
    u += 0x7fffu + ((u >> 16) & 1u);
    return (unsigned short)(u >> 16);
}
__device__ __forceinline__ float wget(const void* p, int i, bool is16) {
    return is16 ? bf2f(((const unsigned short*)p)[i]) : ((const float*)p)[i];
}
__device__ __forceinline__ float rl(float v, int k) {
    return __uint_as_float((unsigned int)__builtin_amdgcn_readlane((int)__float_as_uint(v), k));
}
__device__ __forceinline__ float sigm(float x) {
    x = fminf(fmaxf(x, -30.f), 30.f);
    return 1.f / (1.f + __expf(-x));
}
__device__ __forceinline__ float tanh_f(float x) {
    x = fminf(fmaxf(x, -15.f), 15.f);
    float e = __expf(2.f * x);
    return (e - 1.f) / (e + 1.f);
}
__device__ __forceinline__ float f4e(float4 v, int i) {
    return i == 0 ? v.x : i == 1 ? v.y : i == 2 ? v.z : v.w;
}
__device__ __forceinline__ float4 wld4(const void* p, int row, int kb, bool is16) {
    float4 r;
    int c0 = 4 * kb;
    r.x = (c0 + 0 < H) ? wget(p, row * H + c0 + 0, is16) : 0.f;
    r.y = (c0 + 1 < H) ? wget(p, row * H + c0 + 1, is16) : 0.f;
    r.z = (c0 + 2 < H) ? wget(p, row * H + c0 + 2, is16) : 0.f;
    r.w = (c0 + 3 < H) ? wget(p, row * H + c0 + 3, is16) : 0.f;
    return r;
}

#define L13(M) M(0) M(1) M(2) M(3) M(4) M(5) M(6) M(7) M(8) M(9) M(10) M(11) M(12)
#define L51(M) M(0) M(1) M(2) M(3) M(4) M(5) M(6) M(7) M(8) M(9) \
               M(10) M(11) M(12) M(13) M(14) M(15) M(16) M(17) M(18) M(19) \
               M(20) M(21) M(22) M(23) M(24) M(25) M(26) M(27) M(28) M(29) \
               M(30) M(31) M(32) M(33) M(34) M(35) M(36) M(37) M(38) M(39) \
               M(40) M(41) M(42) M(43) M(44) M(45) M(46) M(47) M(48) M(49) M(50)

extern "C" __global__ void __launch_bounds__(256, 1)
lstm3_kernel(const void* g_in,  const void* g_Wih1, const void* g_Whh1,
             const void* g_bih1, const void* g_bhh1,
             const void* g_Wih2, const void* g_Whh2, const void* g_bih2, const void* g_bhh2,
             const void* g_Wih3, const void* g_Whh3, const void* g_bih3, const void* g_bhh3,
             const void* g_Wlin, const void* g_blin, void* g_out)
{
    extern __shared__ float smem[];

    const int tid  = threadIdx.x;
    const int lane = tid & 63;
    const int wid  = tid >> 6;
    const int e    = blockIdx.x * 4 + wid;
    const int jeff = (lane < H) ? lane : (H - 1);

    // ---- dtype sniff (proven round 1: resolves fp32 on this harness)
    bool is16 = true;
    {
        const unsigned short* p = (const unsigned short*)g_Wih1;
        for (int i = 0; i < 204; ++i) {
            float v = fabsf(bf2f(p[i]));
            if (!(v < 0.2f)) is16 = false;
        }
    }

    // ---- LDS staging: [Whh1 0..203 | Wih2 0..203 | Wih3 0..203 | Whh3 rows 51..203]
    for (int i = tid; i < LDSFL; i += 256) {
        int r = i / PITCH, k = i - r * PITCH;
        const void* src; int srow;
        if (r < 204)      { src = g_Whh1; srow = r; }
        else if (r < 408) { src = g_Wih2; srow = r - 204; }
        else if (r < 612) { src = g_Wih3; srow = r - 408; }
        else              { src = g_Whh3; srow = 51 + (r - 612); }
        smem[i] = (k < H) ? wget(src, srow * H + k, is16) : 0.f;
    }
    __syncthreads();

    // ---- W_hh2 all 4 gates -> AGPRs (204 per lane). "a" constraint pins the
    // live range to the accumulator file; reads below are asm volatile so they
    // stay inside the t-loop (no LICM back into VGPR pressure).
#define AGD(k) float a2i_##k, a2f_##k, a2g_##k, a2o_##k;
    L51(AGD)
#define AGI(k) { \
    float t0 = wget(g_Whh2, (0 * H + jeff) * H + (k), is16); \
    float t1 = wget(g_Whh2, (1 * H + jeff) * H + (k), is16); \
    float t2 = wget(g_Whh2, (2 * H + jeff) * H + (k), is16); \
    float t3 = wget(g_Whh2, (3 * H + jeff) * H + (k), is16); \
    asm volatile("v_accvgpr_write_b32 %0, %1" : "=a"(a2i_##k) : "v"(t0)); \
    asm volatile("v_accvgpr_write_b32 %0, %1" : "=a"(a2f_##k) : "v"(t1)); \
    asm volatile("v_accvgpr_write_b32 %0, %1" : "=a"(a2g_##k) : "v"(t2)); \
    asm volatile("v_accvgpr_write_b32 %0, %1" : "=a"(a2o_##k) : "v"(t3)); }
    L51(AGI)

    // ---- W_hh3 gate i -> 13 named float4 VGPRs (literal-indexed, guaranteed SSA)
#define W3D(kb) float4 w3i_##kb = wld4(g_Whh3, 0 * H + jeff, kb, is16);
    L13(W3D)

    float b1r[4], b2r[4], b3r[4], wi1r[4];
#pragma unroll
    for (int g = 0; g < 4; ++g) {
        int r = g * H + jeff;
        b1r[g]  = wget(g_bih1, r, is16) + wget(g_bhh1, r, is16);
        b2r[g]  = wget(g_bih2, r, is16) + wget(g_bhh2, r, is16);
        b3r[g]  = wget(g_bih3, r, is16) + wget(g_bhh3, r, is16);
        wi1r[g] = wget(g_Wih1, r, is16);
    }
    float wlinr = (lane < H) ? wget(g_Wlin, lane, is16) : 0.f;
    float blinr = wget(g_blin, 0, is16);

    const float4* A1_0 = (const float4*)(smem + (0 * H + jeff) * PITCH);
    const float4* A1_1 = (const float4*)(smem + (1 * H + jeff) * PITCH);
    const float4* A1_2 = (const float4*)(smem + (2 * H + jeff) * PITCH);
    const float4* A1_3 = (const float4*)(smem + (3 * H + jeff) * PITCH);
    const float4* A2_0 = (const float4*)(smem + (204 + 0 * H + jeff) * PITCH);
    const float4* A2_1 = (const float4*)(smem + (204 + 1 * H + jeff) * PITCH);
    const float4* A2_2 = (const float4*)(smem + (204 + 2 * H + jeff) * PITCH);
    const float4* A2_3 = (const float4*)(smem + (204 + 3 * H + jeff) * PITCH);
    const float4* A3_0 = (const float4*)(smem + (408 + 0 * H + jeff) * PITCH);
    const float4* A3_1 = (const float4*)(smem + (408 + 1 * H + jeff) * PITCH);
    const float4* A3_2 = (const float4*)(smem + (408 + 2 * H + jeff) * PITCH);
    const float4* A3_3 = (const float4*)(smem + (408 + 3 * H + jeff) * PITCH);
    const float4* A3f  = (const float4*)(smem + (612 +       jeff) * PITCH);
    const float4* A3g  = (const float4*)(smem + (612 + 51  + jeff) * PITCH);
    const float4* A3o  = (const float4*)(smem + (612 + 102 + jeff) * PITCH);

    float h1 = 0.f, c1 = 0.f, h2 = 0.f, c2 = 0.f, h3 = 0.f, c3 = 0.f;
    float xfb = 0.f;
    const unsigned short* in16 = (const unsigned short*)g_in + (size_t)e * T_IN;
    const float*          in32 = (const float*)g_in          + (size_t)e * T_IN;
    unsigned short*       o16  = (unsigned short*)g_out      + (size_t)e * T_TOT;
    float*                o32  = (float*)g_out               + (size_t)e * T_TOT;

    // ---- layer 1: gates += Whh1 . h1   (LDS)
#define ST1(kb, i) { float hs = rl(h1, 4 * kb + i); \
    a0 = fmaf(f4e(u0, i), hs, a0); a1 = fmaf(f4e(u1, i), hs, a1); \
    a2 = fmaf(f4e(u2, i), hs, a2); a3 = fmaf(f4e(u3, i), hs, a3); }
#define L1KB(kb) { float4 u0 = A1_0[kb], u1 = A1_1[kb], u2 = A1_2[kb], u3 = A1_3[kb]; \
    ST1(kb, 0) ST1(kb, 1) ST1(kb, 2) ST1(kb, 3) }

    // ---- layer 2, LDS pass: gates += Wih2 . h1
#define ST2(kb, i) { float hs = rl(h1, 4 * kb + i); \
    a0 = fmaf(f4e(u0, i), hs, a0); a1 = fmaf(f4e(u1, i), hs, a1); \
    a2 = fmaf(f4e(u2, i), hs, a2); a3 = fmaf(f4e(u3, i), hs, a3); }
#define L2KB(kb) { float4 u0 = A2_0[kb], u1 = A2_1[kb], u2 = A2_2[kb], u3 = A2_3[kb]; \
    ST2(kb, 0) ST2(kb, 1) ST2(kb, 2) ST2(kb, 3) }

    // ---- layer 2, AGPR pass: gates += Whh2 . h2
#define L2A(k) { float hs = rl(h2, k); float w0, w1, w2, w3; \
    asm volatile("v_accvgpr_read_b32 %0, %1" : "=v"(w0) : "a"(a2i_##k)); \
    asm volatile("v_accvgpr_read_b32 %0, %1" : "=v"(w1) : "a"(a2f_##k)); \
    asm volatile("v_accvgpr_read_b32 %0, %1" : "=v"(w2) : "a"(a2g_##k)); \
    asm volatile("v_accvgpr_read_b32 %0, %1" : "=v"(w3) : "a"(a2o_##k)); \
    a0 = fmaf(w0, hs, a0); a1 = fmaf(w1, hs, a1); \
    a2 = fmaf(w2, hs, a2); a3 = fmaf(w3, hs, a3); }

    // ---- layer 3: Wih3 . h2 (LDS) + Whh3{f,g,o} . h3 (LDS) + Whh3{i} . h3 (VGPR)
#define ST3(kb, i) { float hs2 = rl(h2, 4 * kb + i); \
    a0 = fmaf(f4e(u0, i), hs2, a0); a1 = fmaf(f4e(u1, i), hs2, a1); \
    a2 = fmaf(f4e(u2, i), hs2, a2); a3 = fmaf(f4e(u3, i), hs2, a3); \
    float hs3 = rl(h3, 4 * kb + i); \
    a0 = fmaf(f4e(w3i_##kb, i), hs3, a0); a1 = fmaf(f4e(v1, i), hs3, a1); \
    a2 = fmaf(f4e(v2, i), hs3, a2); a3 = fmaf(f4e(v3, i), hs3, a3); }
#define L3KB(kb) { float4 u0 = A3_0[kb], u1 = A3_1[kb], u2 = A3_2[kb], u3 = A3_3[kb]; \
    float4 v1 = A3f[kb], v2 = A3g[kb], v3 = A3o[kb]; \
    ST3(kb, 0) ST3(kb, 1) ST3(kb, 2) ST3(kb, 3) }

#pragma clang loop unroll(disable)
    for (int t = 0; t < T_TOT; ++t) {
        float x = (t < T_IN) ? (is16 ? bf2f(in16[t]) : in32[t]) : xfb;

        float a0, a1, a2, a3;
        // ---------- layer 1 ----------
        a0 = fmaf(wi1r[0], x, b1r[0]);
        a1 = fmaf(wi1r[1], x, b1r[1]);
        a2 = fmaf(wi1r[2], x, b1r[2]);
        a3 = fmaf(wi1r[3], x, b1r[3]);
        L13(L1KB)
        {
            float ig = sigm(a0), fg = sigm(a1), gg = tanh_f(a2), og = sigm(a3);
            c1 = fg * c1 + ig * gg;
            h1 = og * tanh_f(c1);
        }
        // ---------- layer 2 ----------
        a0 = b2r[0]; a1 = b2r[1]; a2 = b2r[2]; a3 = b2r[3];
        L13(L2KB)
        L51(L2A)
        {
            float ig = sigm(a0), fg = sigm(a1), gg = tanh_f(a2), og = sigm(a3);
            c2 = fg * c2 + ig * gg;
            h2 = og * tanh_f(c2);
        }
        // ---------- layer 3 ----------
        a0 = b3r[0]; a1 = b3r[1]; a2 = b3r[2]; a3 = b3r[3];
        L13(L3KB)
        {
            float ig = sigm(a0), fg = sigm(a1), gg = tanh_f(a2), og = sigm(a3);
            c3 = fg * c3 + ig * gg;
            h3 = og * tanh_f(c3);
        }
        // ---------- linear head + feedback ----------
        float s = wlinr * h3;
        s += __shfl_xor(s, 32, 64);
        s += __shfl_xor(s, 16, 64);
        s += __shfl_xor(s, 8, 64);
        s += __shfl_xor(s, 4, 64);
        s += __shfl_xor(s, 2, 64);
        s += __shfl_xor(s, 1, 64);
        float ov = s + blinr;
        xfb = ov;
        if (lane == 0) {
            if (is16) o16[t] = f2bf(ov);
            else      o32[t] = ov;
        }
    }
}

extern "C" void kernel_launch(void* const* d_in, const int* in_sizes, int n_in,
                              void* d_out, int out_size, void* d_ws, size_t ws_size,
                              hipStream_t stream) {
    (void)in_sizes; (void)n_in; (void)d_ws; (void)ws_size; (void)out_size;
    size_t shmem = LDSFL * sizeof(float);   // 159,120 B
    hipFuncSetAttribute((const void*)lstm3_kernel,
                        hipFuncAttributeMaxDynamicSharedMemorySize, (int)shmem);
    lstm3_kernel<<<dim3(256), dim3(256), shmem, stream>>>(
        d_in[0],  d_in[1],  d_in[2],  d_in[3],  d_in[4],
        d_in[5],  d_in[6],  d_in[7],  d_in[8],
        d_in[9],  d_in[10], d_in[11], d_in[12],
        d_in[13], d_in[14], d_out);
}